// Round 14
// baseline (1188.310 us; speedup 1.0000x reference)
//
#include <hip/hip_runtime.h>

// B=8, N=2048, C=512. Flash attention + fp16 MFMA pipeline.
// r14: attn rewritten for LDS-byte reduction: 4 waves x 32q (two Q-frag sets
// per wave share each K-frag b128 read; two P-frags share each G-frag b64
// read) -> per-CU LDS reads halve (256->128KB per 16-key iter). 1 wave/SIMD
// (VGPR ~440) accepted: counted-vmcnt prefetch + softmax||QK ILP hide latency.
// Split-2, kbuf triple [16][512] XOR-swz, gbuf double [512][16] half-swz,
// vmcnt(4) barriers (4 loads/stage). mlp3/final_gemm = r13 pipelined versions.
// ws: [0]=xb->OA [1]=h [2]=l [3]=gT [4]=OB [5]=Wt(2MB)+ml(256KB)

typedef __attribute__((ext_vector_type(4))) float f32x4;
typedef __attribute__((ext_vector_type(8))) short s16x8;      // fp16 bit-patterns
typedef __attribute__((ext_vector_type(4))) short s16x4;
typedef __attribute__((ext_vector_type(8))) _Float16 f16x8;   // MFMA operands
typedef __attribute__((ext_vector_type(4))) _Float16 f16x4;
typedef __attribute__((ext_vector_type(2))) unsigned u32x2;

typedef unsigned int u32;
typedef __attribute__((address_space(1))) const u32 gu32;
typedef __attribute__((address_space(3))) u32 lu32;

__device__ __forceinline__ void gload16(const short* g, short* l) {
  __builtin_amdgcn_global_load_lds((gu32*)g, (lu32*)l, 16, 0, 0);
}

__device__ __forceinline__ short f2h(float f) {
  _Float16 h = (_Float16)f;
  return __builtin_bit_cast(short, h);
}

__device__ __forceinline__ unsigned pk2h(float a, float b) {
  return __builtin_bit_cast(unsigned, __builtin_amdgcn_cvt_pkrtz(a, b));
}

#define MFMA(a, b, c) __builtin_amdgcn_mfma_f32_16x16x32_f16(a, b, c, 0, 0, 0)
#define MFMA16(a, b, c) __builtin_amdgcn_mfma_f32_16x16x16f16(a, b, c, 0, 0, 0)

#define BAR_KEEP4()                                          \
  do {                                                       \
    asm volatile("s_waitcnt vmcnt(4)" ::: "memory");         \
    __builtin_amdgcn_s_barrier();                            \
    __builtin_amdgcn_sched_barrier(0);                       \
  } while (0)
#define BAR_KEEP4_L()                                        \
  do {                                                       \
    asm volatile("s_waitcnt vmcnt(4) lgkmcnt(0)" ::: "memory"); \
    __builtin_amdgcn_s_barrier();                            \
    __builtin_amdgcn_sched_barrier(0);                       \
  } while (0)
#define BAR_VM0()                                            \
  do {                                                       \
    asm volatile("s_waitcnt vmcnt(0)" ::: "memory");         \
    __builtin_amdgcn_s_barrier();                            \
    __builtin_amdgcn_sched_barrier(0);                       \
  } while (0)
#define BAR_ALL()                                            \
  do {                                                       \
    asm volatile("s_waitcnt vmcnt(0) lgkmcnt(0)" ::: "memory"); \
    __builtin_amdgcn_s_barrier();                            \
    __builtin_amdgcn_sched_barrier(0);                       \
  } while (0)

// ---------------- conversion kernels ----------------

__global__ __launch_bounds__(256) void conv_x_kernel(const float* __restrict__ x,
                                                     short* __restrict__ xb) {
  int i = blockIdx.x * 256 + threadIdx.x;
  const float4* xv = (const float4*)x;
  float4 a = xv[2 * i], b = xv[2 * i + 1];
  s16x8 o;
  o[0] = f2h(a.x); o[1] = f2h(a.y); o[2] = f2h(a.z); o[3] = f2h(a.w);
  o[4] = f2h(b.x); o[5] = f2h(b.y); o[6] = f2h(b.z); o[7] = f2h(b.w);
  ((s16x8*)xb)[i] = o;
}

__global__ __launch_bounds__(256) void conv_w_kernel(const float* __restrict__ Wh,
                                                     const float* __restrict__ Wl,
                                                     const float* __restrict__ Wg,
                                                     const float* __restrict__ Wm,
                                                     short* __restrict__ Wt) {
  int idx = blockIdx.x * 256 + threadIdx.x;
  int k = idx & 511, n = (idx >> 9) & 511, w = idx >> 18;
  const float* W = (w == 0) ? Wh : (w == 1) ? Wl : (w == 2) ? Wg : Wm;
  Wt[idx] = f2h(W[k * 512 + n]);
}

// ---------------- fused 3-way MLP GEMM (pipelined, r13) ----------------

__global__ __launch_bounds__(256) void mlp3_kernel(const short* __restrict__ A,
                                                   const short* __restrict__ Wt_all,
                                                   const float* __restrict__ bh,
                                                   const float* __restrict__ bl,
                                                   const float* __restrict__ bg,
                                                   short* __restrict__ h,
                                                   short* __restrict__ l,
                                                   short* __restrict__ gT) {
  int z = blockIdx.z;
  const short* Wt = Wt_all + z * 262144;
  const float* bias = (z == 0) ? bh : (z == 1) ? bl : bg;

  __shared__ __align__(16) short abuf[3][4096];
  __shared__ __align__(16) short bbuf[3][4096];
  int tid = threadIdx.x, lane = tid & 63, w = tid >> 6;
  int wm = w >> 1, wn = w & 1;
  int bm = blockIdx.x * 128, bn = blockIdx.y * 128;
  int rx = lane & 15, g = lane >> 4;

  auto stage = [&](int t) {
    int k0 = t * 32;
    short* ad = &abuf[t % 3][0];
    short* bd = &bbuf[t % 3][0];
    int srow = lane >> 2;
    int scol = ((lane & 3) ^ ((lane >> 3) & 3)) * 8;
#pragma unroll
    for (int j = 0; j < 2; ++j) {
      int wl = w * 2 + j;
      int row = wl * 16 + srow;
      gload16(A + (size_t)(bm + row) * 512 + k0 + scol, ad + wl * 512 + lane * 8);
      gload16(Wt + (size_t)(bn + row) * 512 + k0 + scol, bd + wl * 512 + lane * 8);
    }
  };

  f32x4 acc[4][4];
#pragma unroll
  for (int mi = 0; mi < 4; ++mi)
#pragma unroll
    for (int ni = 0; ni < 4; ++ni) acc[mi][ni] = (f32x4){0.f, 0.f, 0.f, 0.f};

  stage(0); stage(1);
  BAR_KEEP4();

  int foff = rx * 32 + ((g ^ ((rx >> 1) & 3)) << 3);

  for (int t = 0; t < 16; ++t) {
    if (t < 14) stage(t + 2);
    const short* ab = &abuf[t % 3][0];
    const short* bb = &bbuf[t % 3][0];
    f16x8 af[4], bfr[4];
#pragma unroll
    for (int mi = 0; mi < 4; ++mi)
      af[mi] = *(const f16x8*)&ab[(wm * 64 + mi * 16) * 32 + foff];
#pragma unroll
    for (int ni = 0; ni < 4; ++ni)
      bfr[ni] = *(const f16x8*)&bb[(wn * 64 + ni * 16) * 32 + foff];
#pragma unroll
    for (int mi = 0; mi < 4; ++mi)
#pragma unroll
      for (int ni = 0; ni < 4; ++ni) acc[mi][ni] = MFMA(af[mi], bfr[ni], acc[mi][ni]);
    if (t < 14) BAR_KEEP4();
    else if (t == 14) BAR_ALL();
  }

#pragma unroll
  for (int mi = 0; mi < 4; ++mi)
#pragma unroll
    for (int ni = 0; ni < 4; ++ni) {
      int col = bn + wn * 64 + ni * 16 + rx;
      float bv = bias[col];
#pragma unroll
      for (int r = 0; r < 4; ++r) {
        int row = bm + wm * 64 + mi * 16 + g * 4 + r;
        float v = fmaxf(acc[mi][ni][r] + bv, 0.0f);
        short o = f2h(v);
        if (z == 0) h[(size_t)row * 512 + col] = o;
        else if (z == 1) l[(size_t)row * 512 + col] = o;
        else {
          int bb2 = row >> 11, mm = row & 2047;
          gT[((size_t)bb2 * 512 + col) * 2048 + mm] = o;
        }
      }
    }
}

// ---------------- flash attention, split-K, 32q/wave ----------------
// 256 blocks x 256 threads (4 waves x 32 q = 128 q/block), split sp of 1024
// keys, 64 iters of 16 keys. Each K-frag read feeds 2 QK MFMAs (qA,qB);
// each G-frag read feeds 2 PV MFMAs. LDS reads/CU/iter: 128KB (was 256).

__global__ __launch_bounds__(256, 1) void attn_split_kernel(
    const short* __restrict__ lmat, const short* __restrict__ hmat,
    const short* __restrict__ gT,
    short* __restrict__ OA, short* __restrict__ OB,
    float2* __restrict__ mlA, float2* __restrict__ mlB) {
  __shared__ __align__(16) short kbuf[3][8192];  // [16][512] x3, 48KB
  __shared__ __align__(16) short gbuf[2][8192];  // [512][16] x2, 32KB
  int tid = threadIdx.x, lane = tid & 63, w = tid >> 6;  // w in 0..3
  int b = blockIdx.x & 7;
  int idx = blockIdx.x >> 3;        // 0..31
  int qt = idx >> 1, sp = idx & 1;
  int q0 = qt * 128 + w * 32;       // wave owns 32 queries
  int keybase = sp * 1024;
  const short* lb = lmat + (size_t)b * 2048 * 512;
  const short* hb = hmat + (size_t)b * 2048 * 512;
  const short* gb = gT + (size_t)b * 512 * 2048;
  short* Op = sp ? OB : OA;
  float2* ml = sp ? mlB : mlA;

  int r0 = lane & 15, g = lane >> 4;
  int qA = q0 + r0, qB = q0 + 16 + r0;

  // Two Q-frag sets (B-operand): 32 x f16x8 = 128 VGPR
  f16x8 qfA[16], qfB[16];
#pragma unroll
  for (int ks = 0; ks < 16; ++ks) {
    qfA[ks] = *(const f16x8*)&lb[(size_t)qA * 512 + ks * 32 + g * 8];
    qfB[ks] = *(const f16x8*)&lb[(size_t)qB * 512 + ks * 32 + g * 8];
  }
  f32x4 accA[32], accB[32];  // O^T per query-half: 256 VGPR
#pragma unroll
  for (int i = 0; i < 32; ++i) {
    accA[i] = (f32x4){0.f, 0.f, 0.f, 0.f};
    accB[i] = (f32x4){0.f, 0.f, 0.f, 0.f};
  }
  float mrA = -3e38f, mrB = -3e38f, lsA = 0.f, lsB = 0.f;

  // staging: 4 gload16 per wave per tile (4 waves cover 16 rows / 16 chunks)
  auto stageK = [&](int t) {
    int key0 = keybase + t * 16;
    short* kd = &kbuf[t % 3][0];
#pragma unroll
    for (int j = 0; j < 4; ++j) {
      int wl = w * 4 + j;
      gload16(hb + (size_t)(key0 + wl) * 512 + (((lane * 16) ^ ((wl & 7) << 4)) >> 1),
              kd + wl * 512);
    }
  };
  auto stageG = [&](int t) {
    int key0 = keybase + t * 16;
    short* gd = &gbuf[t & 1][0];
#pragma unroll
    for (int j = 0; j < 4; ++j) {
      int wl = w * 4 + j;
      int c = wl * 32 + (lane >> 1);
      int half = (lane & 1) ^ ((lane >> 3) & 1);
      gload16(gb + (size_t)c * 2048 + key0 + half * 8, gd + wl * 512);
    }
  };
  auto QK = [&](int t, f32x4& oA, f32x4& oB) {
    const short* kb = &kbuf[t % 3][0];
#pragma unroll
    for (int ks = 0; ks < 16; ++ks) {
      f16x8 kf = *(const f16x8*)&kb[(r0 * 512 + ks * 32 + g * 8) ^ ((r0 & 7) << 3)];
      oA = MFMA(kf, qfA[ks], oA);
      oB = MFMA(kf, qfB[ks], oB);
    }
  };

  stageK(0); stageK(1); stageG(0); stageK(2);
  BAR_KEEP4();
  f32x4 scA = {0.f, 0.f, 0.f, 0.f}, scB = {0.f, 0.f, 0.f, 0.f};
  QK(0, scA, scB);
  BAR_KEEP4();

  int goff = r0 * 16 + (((g >> 1) ^ ((r0 >> 2) & 1)) << 3) + ((g & 1) << 2);

  for (int t = 0; t < 64; ++t) {
    if (t < 63) stageG(t + 1);
    if (t < 61) stageK(t + 3);

    f32x4 snA = {0.f, 0.f, 0.f, 0.f}, snB = {0.f, 0.f, 0.f, 0.f};
    if (t < 63) {
      __builtin_amdgcn_s_setprio(1);
      QK(t + 1, snA, snB);
      __builtin_amdgcn_s_setprio(0);
    }

    // ---- softmax(t) for both query halves ----
    float mA = fmaxf(fmaxf(scA[0], scA[1]), fmaxf(scA[2], scA[3]));
    float mB = fmaxf(fmaxf(scB[0], scB[1]), fmaxf(scB[2], scB[3]));
    mA = fmaxf(mA, __shfl_xor(mA, 16)); mA = fmaxf(mA, __shfl_xor(mA, 32));
    mB = fmaxf(mB, __shfl_xor(mB, 16)); mB = fmaxf(mB, __shfl_xor(mB, 32));
    bool ok = (mA <= mrA + 8.0f) && (mB <= mrB + 8.0f);  // defer-max THR=8
    if (!__all((int)ok)) {
      float nA = fmaxf(mrA, mA), nB = fmaxf(mrB, mB);
      float sA = __expf(mrA - nA), sB = __expf(mrB - nB);
      mrA = nA; mrB = nB;
      lsA *= sA; lsB *= sB;
#pragma unroll
      for (int nf = 0; nf < 32; ++nf) { accA[nf] *= sA; accB[nf] *= sB; }
    }
    float a0 = __expf(scA[0] - mrA), a1 = __expf(scA[1] - mrA);
    float a2 = __expf(scA[2] - mrA), a3 = __expf(scA[3] - mrA);
    float b0 = __expf(scB[0] - mrB), b1 = __expf(scB[1] - mrB);
    float b2 = __expf(scB[2] - mrB), b3 = __expf(scB[3] - mrB);
    lsA += (a0 + a1) + (a2 + a3);
    lsB += (b0 + b1) + (b2 + b3);

    u32x2 pwA = {pk2h(a0, a1), pk2h(a2, a3)};
    u32x2 pwB = {pk2h(b0, b1), pk2h(b2, b3)};
    f16x4 pfA = __builtin_bit_cast(f16x4, pwA);
    f16x4 pfB = __builtin_bit_cast(f16x4, pwB);

    // ---- PV(t): each G-frag read feeds both query halves ----
    const short* gp = &gbuf[t & 1][goff];
    __builtin_amdgcn_s_setprio(1);
#pragma unroll
    for (int nf = 0; nf < 32; ++nf) {
      f16x4 gf = *(const f16x4*)&gp[nf * 256];
      accA[nf] = MFMA16(gf, pfA, accA[nf]);
      accB[nf] = MFMA16(gf, pfB, accB[nf]);
    }
    __builtin_amdgcn_s_setprio(0);

    if (t < 61) BAR_KEEP4(); else BAR_VM0();
    scA = snA; scB = snB;
  }

  // ---- epilogue ----
  lsA += __shfl_xor(lsA, 16); lsA += __shfl_xor(lsA, 32);
  lsB += __shfl_xor(lsB, 16); lsB += __shfl_xor(lsB, 32);
  float invA = 1.0f / lsA, invB = 1.0f / lsB;
#pragma unroll
  for (int nf = 0; nf < 32; ++nf) {
    s16x4 oA4, oB4;
    oA4[0] = f2h(accA[nf][0] * invA); oA4[1] = f2h(accA[nf][1] * invA);
    oA4[2] = f2h(accA[nf][2] * invA); oA4[3] = f2h(accA[nf][3] * invA);
    oB4[0] = f2h(accB[nf][0] * invB); oB4[1] = f2h(accB[nf][1] * invB);
    oB4[2] = f2h(accB[nf][2] * invB); oB4[3] = f2h(accB[nf][3] * invB);
    *(s16x4*)&Op[((size_t)b * 2048 + qA) * 512 + nf * 16 + g * 4] = oA4;
    *(s16x4*)&Op[((size_t)b * 2048 + qB) * 512 + nf * 16 + g * 4] = oB4;
  }
  if (g == 0) {
    ml[(size_t)b * 2048 + qA] = make_float2(mrA, lsA);
    ml[(size_t)b * 2048 + qB] = make_float2(mrB, lsB);
  }
}

// ---------------- fused combine + final GEMM (pipelined, r13) ----------------

__global__ __launch_bounds__(256) void final_gemm_kernel(
    const short* __restrict__ OA, const short* __restrict__ OB,
    const float2* __restrict__ mlA, const float2* __restrict__ mlB,
    const float* __restrict__ x, const short* __restrict__ Wt,
    const float* __restrict__ bias, float* __restrict__ out) {
  __shared__ __align__(16) short abuf[2][4096];
  __shared__ __align__(16) short bbuf[3][4096];
  int tid = threadIdx.x, lane = tid & 63, w = tid >> 6;
  int wm = w >> 1, wn = w & 1;
  int bm = blockIdx.x * 128, bn = blockIdx.y * 128;
  int rx = lane & 15, g = lane >> 4;

  float wgt[2][2];
#pragma unroll
  for (int it = 0; it < 2; ++it) {
    int row = (tid >> 2) + it * 64;
    float2 a2 = mlA[bm + row], b2 = mlB[bm + row];
    float ms = fmaxf(a2.x, b2.x);
    float wA = __expf(a2.x - ms) * a2.y;
    float wB = __expf(b2.x - ms) * b2.y;
    float winv = 1.0f / (wA + wB);
    wgt[it][0] = wA * winv;
    wgt[it][1] = wB * winv;
  }

  auto stageB = [&](int t) {
    int k0 = t * 32;
    short* bd = &bbuf[t % 3][0];
    int srow = lane >> 2;
    int scol = ((lane & 3) ^ ((lane >> 3) & 3)) * 8;
#pragma unroll
    for (int j = 0; j < 2; ++j) {
      int wl = w * 2 + j;
      int row = wl * 16 + srow;
      gload16(Wt + (size_t)(bn + row) * 512 + k0 + scol, bd + wl * 512 + lane * 8);
    }
  };
  auto loadA = [&](int t, s16x8 av[2]) {
#pragma unroll
    for (int it = 0; it < 2; ++it) {
      int c = tid + it * 256;
      int row = c >> 2, col8 = (c & 3) * 8;
      size_t base = (size_t)(bm + row) * 512 + t * 32 + col8;
      f16x8 oa = *(const f16x8*)&OA[base];
      f16x8 ob = *(const f16x8*)&OB[base];
      float4 x0 = *(const float4*)&x[base];
      float4 x1 = *(const float4*)&x[base + 4];
      float wA = wgt[it][0], wB = wgt[it][1];
      s16x8 v;
      v[0] = f2h((float)oa[0] * wA + (float)ob[0] * wB + x0.x);
      v[1] = f2h((float)oa[1] * wA + (float)ob[1] * wB + x0.y);
      v[2] = f2h((float)oa[2] * wA + (float)ob[2] * wB + x0.z);
      v[3] = f2h((float)oa[3] * wA + (float)ob[3] * wB + x0.w);
      v[4] = f2h((float)oa[4] * wA + (float)ob[4] * wB + x1.x);
      v[5] = f2h((float)oa[5] * wA + (float)ob[5] * wB + x1.y);
      v[6] = f2h((float)oa[6] * wA + (float)ob[6] * wB + x1.z);
      v[7] = f2h((float)oa[7] * wA + (float)ob[7] * wB + x1.w);
      av[it] = v;
    }
  };
  auto writeA = [&](int t, s16x8 av[2]) {
    short* ad = &abuf[t & 1][0];
#pragma unroll
    for (int it = 0; it < 2; ++it) {
      int c = tid + it * 256;
      int row = c >> 2;
      int chunk_p = (c & 3) ^ ((row >> 1) & 3);
      *(s16x8*)&ad[row * 32 + chunk_p * 8] = av[it];
    }
  };

  f32x4 acc[4][4];
#pragma unroll
  for (int mi = 0; mi < 4; ++mi)
#pragma unroll
    for (int ni = 0; ni < 4; ++ni) acc[mi][ni] = (f32x4){0.f, 0.f, 0.f, 0.f};

  s16x8 av[2];
  loadA(0, av);
  stageB(0); stageB(1);
  writeA(0, av);
  BAR_KEEP4_L();

  int foff = rx * 32 + ((g ^ ((rx >> 1) & 3)) << 3);

  for (int t = 0; t < 16; ++t) {
    if (t < 15) loadA(t + 1, av);
    if (t < 14) stageB(t + 2);
    const short* ab = &abuf[t & 1][0];
    const short* bb = &bbuf[t % 3][0];
    f16x8 af[4], bfr[4];
#pragma unroll
    for (int mi = 0; mi < 4; ++mi)
      af[mi] = *(const f16x8*)&ab[(wm * 64 + mi * 16) * 32 + foff];
#pragma unroll
    for (int ni = 0; ni < 4; ++ni)
      bfr[ni] = *(const f16x8*)&bb[(wn * 64 + ni * 16) * 32 + foff];
#pragma unroll
    for (int mi = 0; mi < 4; ++mi)
#pragma unroll
      for (int ni = 0; ni < 4; ++ni) acc[mi][ni] = MFMA(af[mi], bfr[ni], acc[mi][ni]);
    if (t < 15) writeA(t + 1, av);
    if (t < 14) BAR_KEEP4_L();
    else if (t == 14) BAR_ALL();
  }

#pragma unroll
  for (int mi = 0; mi < 4; ++mi)
#pragma unroll
    for (int ni = 0; ni < 4; ++ni) {
      int col = bn + wn * 64 + ni * 16 + rx;
      float bv = bias[col];
#pragma unroll
      for (int r = 0; r < 4; ++r) {
        int row = bm + wm * 64 + mi * 16 + g * 4 + r;
        out[(size_t)row * 512 + col] = fmaxf(acc[mi][ni][r] + bv, 0.0f);
      }
    }
}

// ---------------- host launch ----------------

extern "C" void kernel_launch(void* const* d_in, const int* in_sizes, int n_in,
                              void* d_out, int out_size, void* d_ws, size_t ws_size,
                              hipStream_t stream) {
  const float* x  = (const float*)d_in[0];
  const float* Wh = (const float*)d_in[1];
  const float* bh = (const float*)d_in[2];
  const float* Wl = (const float*)d_in[3];
  const float* bl = (const float*)d_in[4];
  const float* Wg = (const float*)d_in[5];
  const float* bg = (const float*)d_in[6];
  const float* Wm = (const float*)d_in[7];
  const float* bm = (const float*)d_in[8];

  char* ws = (char*)d_ws;
  const size_t SZ = 16777216;
  short*  xb  = (short*)(ws + 0 * SZ);   // conv_x out; reused as OA by attn
  short*  h   = (short*)(ws + 1 * SZ);
  short*  l   = (short*)(ws + 2 * SZ);
  short*  gT  = (short*)(ws + 3 * SZ);
  short*  OB  = (short*)(ws + 4 * SZ);
  short*  Wt  = (short*)(ws + 5 * SZ);   // 2 MB
  float2* mlA = (float2*)(ws + 5 * SZ + 2097152);            // 128 KB
  float2* mlB = (float2*)(ws + 5 * SZ + 2097152 + 131072);   // 128 KB

  conv_x_kernel<<<4096, 256, 0, stream>>>(x, xb);
  conv_w_kernel<<<4096, 256, 0, stream>>>(Wh, Wl, Wg, Wm, Wt);
  mlp3_kernel<<<dim3(128, 4, 3), 256, 0, stream>>>(xb, Wt, bh, bl, bg, h, l, gT);
  attn_split_kernel<<<256, 256, 0, stream>>>(l, h, gT, xb, OB, mlA, mlB);
  final_gemm_kernel<<<dim3(128, 4), 256, 0, stream>>>(xb, OB, mlA, mlB, x,
                                                      Wt + 3 * 262144, bm,
                                                      (float*)d_out);
}

// Round 15
// 232.176 us; speedup vs baseline: 5.1182x; 5.1182x over previous
//
#include <hip/hip_runtime.h>

// B=8, N=2048, C=512. Flash attention + fp16 MFMA pipeline.
// r15: r13 revert (r14's 32q/wave spilled: VGPR capped 256, need ~440) +
// conv_x fused into mlp3 (A reg-staged from f32 x with on-the-fly cvt,
// final_gemm's proven loadA/writeA pattern; x re-reads are L3-resident).
// attn = r12/r13 winner, byte-identical. final_gemm = r13.
// ws: [0]=OA [1]=h [2]=l [3]=gT [4]=OB [5]=Wt(2MB)+ml(256KB)

typedef __attribute__((ext_vector_type(4))) float f32x4;
typedef __attribute__((ext_vector_type(8))) short s16x8;      // fp16 bit-patterns
typedef __attribute__((ext_vector_type(4))) short s16x4;
typedef __attribute__((ext_vector_type(8))) _Float16 f16x8;   // MFMA operands
typedef __attribute__((ext_vector_type(4))) _Float16 f16x4;
typedef __attribute__((ext_vector_type(2))) unsigned u32x2;

typedef unsigned int u32;
typedef __attribute__((address_space(1))) const u32 gu32;
typedef __attribute__((address_space(3))) u32 lu32;

__device__ __forceinline__ void gload16(const short* g, short* l) {
  __builtin_amdgcn_global_load_lds((gu32*)g, (lu32*)l, 16, 0, 0);
}

__device__ __forceinline__ short f2h(float f) {
  _Float16 h = (_Float16)f;
  return __builtin_bit_cast(short, h);
}

__device__ __forceinline__ unsigned pk2h(float a, float b) {
  return __builtin_bit_cast(unsigned, __builtin_amdgcn_cvt_pkrtz(a, b));
}

#define MFMA(a, b, c) __builtin_amdgcn_mfma_f32_16x16x32_f16(a, b, c, 0, 0, 0)
#define MFMA16(a, b, c) __builtin_amdgcn_mfma_f32_16x16x16f16(a, b, c, 0, 0, 0)

#define BAR_KEEP2()                                          \
  do {                                                       \
    asm volatile("s_waitcnt vmcnt(2)" ::: "memory");         \
    __builtin_amdgcn_s_barrier();                            \
    __builtin_amdgcn_sched_barrier(0);                       \
  } while (0)
#define BAR_KEEP2_L()                                        \
  do {                                                       \
    asm volatile("s_waitcnt vmcnt(2) lgkmcnt(0)" ::: "memory"); \
    __builtin_amdgcn_s_barrier();                            \
    __builtin_amdgcn_sched_barrier(0);                       \
  } while (0)
#define BAR_KEEP4_L()                                        \
  do {                                                       \
    asm volatile("s_waitcnt vmcnt(4) lgkmcnt(0)" ::: "memory"); \
    __builtin_amdgcn_s_barrier();                            \
    __builtin_amdgcn_sched_barrier(0);                       \
  } while (0)
#define BAR_VM0()                                            \
  do {                                                       \
    asm volatile("s_waitcnt vmcnt(0)" ::: "memory");         \
    __builtin_amdgcn_s_barrier();                            \
    __builtin_amdgcn_sched_barrier(0);                       \
  } while (0)
#define BAR_ALL()                                            \
  do {                                                       \
    asm volatile("s_waitcnt vmcnt(0) lgkmcnt(0)" ::: "memory"); \
    __builtin_amdgcn_s_barrier();                            \
    __builtin_amdgcn_sched_barrier(0);                       \
  } while (0)

// ---------------- weight conversion ----------------

__global__ __launch_bounds__(256) void conv_w_kernel(const float* __restrict__ Wh,
                                                     const float* __restrict__ Wl,
                                                     const float* __restrict__ Wg,
                                                     const float* __restrict__ Wm,
                                                     short* __restrict__ Wt) {
  int idx = blockIdx.x * 256 + threadIdx.x;
  int k = idx & 511, n = (idx >> 9) & 511, w = idx >> 18;
  const float* W = (w == 0) ? Wh : (w == 1) ? Wl : (w == 2) ? Wg : Wm;
  Wt[idx] = f2h(W[k * 512 + n]);
}

// ---------------- fused cvt + 3-way MLP GEMM (pipelined) ----------------
// grid (128,4,3), 256 threads. A staged from f32 x via regs (cvt fused,
// issue-early/write-late); B via gload16 triple-buffer. vmcnt(2) barriers.

__global__ __launch_bounds__(256) void mlp3_kernel(const float* __restrict__ x,
                                                   const short* __restrict__ Wt_all,
                                                   const float* __restrict__ bh,
                                                   const float* __restrict__ bl,
                                                   const float* __restrict__ bg,
                                                   short* __restrict__ h,
                                                   short* __restrict__ l,
                                                   short* __restrict__ gT) {
  int z = blockIdx.z;
  const short* Wt = Wt_all + z * 262144;
  const float* bias = (z == 0) ? bh : (z == 1) ? bl : bg;

  __shared__ __align__(16) short abuf[2][4096];
  __shared__ __align__(16) short bbuf[3][4096];
  int tid = threadIdx.x, lane = tid & 63, w = tid >> 6;
  int wm = w >> 1, wn = w & 1;
  int bm = blockIdx.x * 128, bn = blockIdx.y * 128;
  int rx = lane & 15, g = lane >> 4;

  auto stageB = [&](int t) {
    int k0 = t * 32;
    short* bd = &bbuf[t % 3][0];
    int srow = lane >> 2;
    int scol = ((lane & 3) ^ ((lane >> 3) & 3)) * 8;
#pragma unroll
    for (int j = 0; j < 2; ++j) {
      int wl = w * 2 + j;
      int row = wl * 16 + srow;
      gload16(Wt + (size_t)(bn + row) * 512 + k0 + scol, bd + wl * 512 + lane * 8);
    }
  };
  // A: load f32 slice, cvt to fp16 in regs (issued early), ds_write late.
  auto loadA = [&](int t, s16x8 av[2]) {
#pragma unroll
    for (int it = 0; it < 2; ++it) {
      int c = tid + it * 256;
      int row = c >> 2, col8 = (c & 3) * 8;
      size_t base = (size_t)(bm + row) * 512 + t * 32 + col8;
      float4 x0 = *(const float4*)&x[base];
      float4 x1 = *(const float4*)&x[base + 4];
      s16x8 v;
      v[0] = f2h(x0.x); v[1] = f2h(x0.y); v[2] = f2h(x0.z); v[3] = f2h(x0.w);
      v[4] = f2h(x1.x); v[5] = f2h(x1.y); v[6] = f2h(x1.z); v[7] = f2h(x1.w);
      av[it] = v;
    }
  };
  auto writeA = [&](int t, s16x8 av[2]) {
    short* ad = &abuf[t & 1][0];
#pragma unroll
    for (int it = 0; it < 2; ++it) {
      int c = tid + it * 256;
      int row = c >> 2;
      int chunk_p = (c & 3) ^ ((row >> 1) & 3);
      *(s16x8*)&ad[row * 32 + chunk_p * 8] = av[it];
    }
  };

  f32x4 acc[4][4];
#pragma unroll
  for (int mi = 0; mi < 4; ++mi)
#pragma unroll
    for (int ni = 0; ni < 4; ++ni) acc[mi][ni] = (f32x4){0.f, 0.f, 0.f, 0.f};

  s16x8 av[2];
  loadA(0, av);
  stageB(0); stageB(1);
  writeA(0, av);
  BAR_KEEP2_L();  // drains B(0) + A writes, keeps B(1)

  int foff = rx * 32 + ((g ^ ((rx >> 1) & 3)) << 3);

  for (int t = 0; t < 16; ++t) {
    if (t < 15) loadA(t + 1, av);
    if (t < 14) stageB(t + 2);
    const short* ab = &abuf[t & 1][0];
    const short* bb = &bbuf[t % 3][0];
    f16x8 af[4], bfr[4];
#pragma unroll
    for (int mi = 0; mi < 4; ++mi)
      af[mi] = *(const f16x8*)&ab[(wm * 64 + mi * 16) * 32 + foff];
#pragma unroll
    for (int ni = 0; ni < 4; ++ni)
      bfr[ni] = *(const f16x8*)&bb[(wn * 64 + ni * 16) * 32 + foff];
#pragma unroll
    for (int mi = 0; mi < 4; ++mi)
#pragma unroll
      for (int ni = 0; ni < 4; ++ni) acc[mi][ni] = MFMA(af[mi], bfr[ni], acc[mi][ni]);
    if (t < 15) writeA(t + 1, av);
    if (t < 14) BAR_KEEP2_L();
    else if (t == 14) BAR_ALL();
  }

#pragma unroll
  for (int mi = 0; mi < 4; ++mi)
#pragma unroll
    for (int ni = 0; ni < 4; ++ni) {
      int col = bn + wn * 64 + ni * 16 + rx;
      float bv = bias[col];
#pragma unroll
      for (int r = 0; r < 4; ++r) {
        int row = bm + wm * 64 + mi * 16 + g * 4 + r;
        float v = fmaxf(acc[mi][ni][r] + bv, 0.0f);
        short o = f2h(v);
        if (z == 0) h[(size_t)row * 512 + col] = o;
        else if (z == 1) l[(size_t)row * 512 + col] = o;
        else {
          int bb2 = row >> 11, mm = row & 2047;
          gT[((size_t)bb2 * 512 + col) * 2048 + mm] = o;
        }
      }
    }
}

// ---------------- flash attention, split-K (r12/r13 winner) ----------------

__global__ __launch_bounds__(512, 1) void attn_split_kernel(
    const short* __restrict__ lmat, const short* __restrict__ hmat,
    const short* __restrict__ gT,
    short* __restrict__ OA, short* __restrict__ OB,
    float2* __restrict__ mlA, float2* __restrict__ mlB) {
  __shared__ __align__(16) short kbuf[3][8192];  // 48KB
  __shared__ __align__(16) short gbuf[2][8192];  // 32KB
  int tid = threadIdx.x, lane = tid & 63, w = tid >> 6;  // w in 0..7
  int b = blockIdx.x & 7;
  int idx = blockIdx.x >> 3;
  int qt = idx >> 1, sp = idx & 1;
  int q0 = qt * 128 + w * 16;
  int keybase = sp * 1024;
  const short* lb = lmat + (size_t)b * 2048 * 512;
  const short* hb = hmat + (size_t)b * 2048 * 512;
  const short* gb = gT + (size_t)b * 512 * 2048;
  short* Op = sp ? OB : OA;
  float2* ml = sp ? mlB : mlA;

  int r0 = lane & 15, g = lane >> 4;

  f16x8 qf[16];
  {
    int q = q0 + r0;
#pragma unroll
    for (int ks = 0; ks < 16; ++ks)
      qf[ks] = *(const f16x8*)&lb[(size_t)q * 512 + ks * 32 + g * 8];
  }
  f32x4 accO[32];
#pragma unroll
  for (int i = 0; i < 32; ++i) accO[i] = (f32x4){0.f, 0.f, 0.f, 0.f};
  float mrun = -3e38f, lsumL = 0.f;

  auto stageK = [&](int t) {
    int key0 = keybase + t * 16;
    short* kd = &kbuf[t % 3][0];
#pragma unroll
    for (int j = 0; j < 2; ++j) {
      int wl = w * 2 + j;
      gload16(hb + (size_t)(key0 + wl) * 512 + (((lane * 16) ^ ((wl & 7) << 4)) >> 1),
              kd + wl * 512);
    }
  };
  auto stageG = [&](int t) {
    int key0 = keybase + t * 16;
    short* gd = &gbuf[t & 1][0];
#pragma unroll
    for (int j = 0; j < 2; ++j) {
      int wl = w * 2 + j;
      int c = wl * 32 + (lane >> 1);
      int half = (lane & 1) ^ ((lane >> 3) & 1);
      gload16(gb + (size_t)c * 2048 + key0 + half * 8, gd + wl * 512);
    }
  };
  auto QK = [&](int t, f32x4& o) {
    const short* kb = &kbuf[t % 3][0];
#pragma unroll
    for (int ks = 0; ks < 16; ++ks) {
      f16x8 kf = *(const f16x8*)&kb[(r0 * 512 + ks * 32 + g * 8) ^ ((r0 & 7) << 3)];
      o = MFMA(kf, qf[ks], o);
    }
  };

  stageK(0); stageK(1); stageG(0); stageK(2);
  BAR_KEEP2();
  f32x4 sc = {0.f, 0.f, 0.f, 0.f};
  QK(0, sc);
  BAR_KEEP2();

  int goff = r0 * 16 + (((g >> 1) ^ ((r0 >> 2) & 1)) << 3) + ((g & 1) << 2);

  for (int t = 0; t < 64; ++t) {
    if (t < 63) stageG(t + 1);
    if (t < 61) stageK(t + 3);

    f32x4 sn = {0.f, 0.f, 0.f, 0.f};
    if (t < 63) {
      __builtin_amdgcn_s_setprio(1);
      QK(t + 1, sn);
      __builtin_amdgcn_s_setprio(0);
    }

    float m2 = fmaxf(fmaxf(sc[0], sc[1]), fmaxf(sc[2], sc[3]));
    m2 = fmaxf(m2, __shfl_xor(m2, 16));
    m2 = fmaxf(m2, __shfl_xor(m2, 32));
    bool ok = (m2 <= mrun + 8.0f);
    if (!__all((int)ok)) {
      float mnew = fmaxf(mrun, m2);
      float s = __expf(mrun - mnew);
      mrun = mnew;
      lsumL *= s;
#pragma unroll
      for (int nf = 0; nf < 32; ++nf) accO[nf] *= s;
    }
    float p0 = __expf(sc[0] - mrun), p1 = __expf(sc[1] - mrun);
    float p2 = __expf(sc[2] - mrun), p3 = __expf(sc[3] - mrun);
    lsumL += (p0 + p1) + (p2 + p3);

    u32x2 pw = {pk2h(p0, p1), pk2h(p2, p3)};
    f16x4 pfrag = __builtin_bit_cast(f16x4, pw);

    const short* gp = &gbuf[t & 1][goff];
    __builtin_amdgcn_s_setprio(1);
#pragma unroll
    for (int nf = 0; nf < 32; ++nf) {
      f16x4 gf = *(const f16x4*)&gp[nf * 256];
      accO[nf] = MFMA16(gf, pfrag, accO[nf]);
    }
    __builtin_amdgcn_s_setprio(0);

    if (t < 61) BAR_KEEP2(); else BAR_VM0();
    sc = sn;
  }

  float ls = lsumL;
  ls += __shfl_xor(ls, 16);
  ls += __shfl_xor(ls, 32);
  float inv = 1.0f / ls;
  int q = q0 + r0;
#pragma unroll
  for (int nf = 0; nf < 32; ++nf) {
    s16x4 o;
    o[0] = f2h(accO[nf][0] * inv);
    o[1] = f2h(accO[nf][1] * inv);
    o[2] = f2h(accO[nf][2] * inv);
    o[3] = f2h(accO[nf][3] * inv);
    *(s16x4*)&Op[((size_t)b * 2048 + q) * 512 + nf * 16 + g * 4] = o;
  }
  if (g == 0) ml[(size_t)b * 2048 + q] = make_float2(mrun, ls);
}

// ---------------- fused combine + final GEMM (pipelined, r13) ----------------

__global__ __launch_bounds__(256) void final_gemm_kernel(
    const short* __restrict__ OA, const short* __restrict__ OB,
    const float2* __restrict__ mlA, const float2* __restrict__ mlB,
    const float* __restrict__ x, const short* __restrict__ Wt,
    const float* __restrict__ bias, float* __restrict__ out) {
  __shared__ __align__(16) short abuf[2][4096];
  __shared__ __align__(16) short bbuf[3][4096];
  int tid = threadIdx.x, lane = tid & 63, w = tid >> 6;
  int wm = w >> 1, wn = w & 1;
  int bm = blockIdx.x * 128, bn = blockIdx.y * 128;
  int rx = lane & 15, g = lane >> 4;

  float wgt[2][2];
#pragma unroll
  for (int it = 0; it < 2; ++it) {
    int row = (tid >> 2) + it * 64;
    float2 a2 = mlA[bm + row], b2 = mlB[bm + row];
    float ms = fmaxf(a2.x, b2.x);
    float wA = __expf(a2.x - ms) * a2.y;
    float wB = __expf(b2.x - ms) * b2.y;
    float winv = 1.0f / (wA + wB);
    wgt[it][0] = wA * winv;
    wgt[it][1] = wB * winv;
  }

  auto stageB = [&](int t) {
    int k0 = t * 32;
    short* bd = &bbuf[t % 3][0];
    int srow = lane >> 2;
    int scol = ((lane & 3) ^ ((lane >> 3) & 3)) * 8;
#pragma unroll
    for (int j = 0; j < 2; ++j) {
      int wl = w * 2 + j;
      int row = wl * 16 + srow;
      gload16(Wt + (size_t)(bn + row) * 512 + k0 + scol, bd + wl * 512 + lane * 8);
    }
  };
  auto loadA = [&](int t, s16x8 av[2]) {
#pragma unroll
    for (int it = 0; it < 2; ++it) {
      int c = tid + it * 256;
      int row = c >> 2, col8 = (c & 3) * 8;
      size_t base = (size_t)(bm + row) * 512 + t * 32 + col8;
      f16x8 oa = *(const f16x8*)&OA[base];
      f16x8 ob = *(const f16x8*)&OB[base];
      float4 x0 = *(const float4*)&x[base];
      float4 x1 = *(const float4*)&x[base + 4];
      float wA = wgt[it][0], wB = wgt[it][1];
      s16x8 v;
      v[0] = f2h((float)oa[0] * wA + (float)ob[0] * wB + x0.x);
      v[1] = f2h((float)oa[1] * wA + (float)ob[1] * wB + x0.y);
      v[2] = f2h((float)oa[2] * wA + (float)ob[2] * wB + x0.z);
      v[3] = f2h((float)oa[3] * wA + (float)ob[3] * wB + x0.w);
      v[4] = f2h((float)oa[4] * wA + (float)ob[4] * wB + x1.x);
      v[5] = f2h((float)oa[5] * wA + (float)ob[5] * wB + x1.y);
      v[6] = f2h((float)oa[6] * wA + (float)ob[6] * wB + x1.z);
      v[7] = f2h((float)oa[7] * wA + (float)ob[7] * wB + x1.w);
      av[it] = v;
    }
  };
  auto writeA = [&](int t, s16x8 av[2]) {
    short* ad = &abuf[t & 1][0];
#pragma unroll
    for (int it = 0; it < 2; ++it) {
      int c = tid + it * 256;
      int row = c >> 2;
      int chunk_p = (c & 3) ^ ((row >> 1) & 3);
      *(s16x8*)&ad[row * 32 + chunk_p * 8] = av[it];
    }
  };

  f32x4 acc[4][4];
#pragma unroll
  for (int mi = 0; mi < 4; ++mi)
#pragma unroll
    for (int ni = 0; ni < 4; ++ni) acc[mi][ni] = (f32x4){0.f, 0.f, 0.f, 0.f};

  s16x8 av[2];
  loadA(0, av);
  stageB(0); stageB(1);
  writeA(0, av);
  BAR_KEEP4_L();

  int foff = rx * 32 + ((g ^ ((rx >> 1) & 3)) << 3);

  for (int t = 0; t < 16; ++t) {
    if (t < 15) loadA(t + 1, av);
    if (t < 14) stageB(t + 2);
    const short* ab = &abuf[t & 1][0];
    const short* bb = &bbuf[t % 3][0];
    f16x8 af[4], bfr[4];
#pragma unroll
    for (int mi = 0; mi < 4; ++mi)
      af[mi] = *(const f16x8*)&ab[(wm * 64 + mi * 16) * 32 + foff];
#pragma unroll
    for (int ni = 0; ni < 4; ++ni)
      bfr[ni] = *(const f16x8*)&bb[(wn * 64 + ni * 16) * 32 + foff];
#pragma unroll
    for (int mi = 0; mi < 4; ++mi)
#pragma unroll
      for (int ni = 0; ni < 4; ++ni) acc[mi][ni] = MFMA(af[mi], bfr[ni], acc[mi][ni]);
    if (t < 15) writeA(t + 1, av);
    if (t < 14) BAR_KEEP4_L();
    else if (t == 14) BAR_ALL();
  }

#pragma unroll
  for (int mi = 0; mi < 4; ++mi)
#pragma unroll
    for (int ni = 0; ni < 4; ++ni) {
      int col = bn + wn * 64 + ni * 16 + rx;
      float bv = bias[col];
#pragma unroll
      for (int r = 0; r < 4; ++r) {
        int row = bm + wm * 64 + mi * 16 + g * 4 + r;
        out[(size_t)row * 512 + col] = fmaxf(acc[mi][ni][r] + bv, 0.0f);
      }
    }
}

// ---------------- host launch ----------------

extern "C" void kernel_launch(void* const* d_in, const int* in_sizes, int n_in,
                              void* d_out, int out_size, void* d_ws, size_t ws_size,
                              hipStream_t stream) {
  const float* x  = (const float*)d_in[0];
  const float* Wh = (const float*)d_in[1];
  const float* bh = (const float*)d_in[2];
  const float* Wl = (const float*)d_in[3];
  const float* bl = (const float*)d_in[4];
  const float* Wg = (const float*)d_in[5];
  const float* bg = (const float*)d_in[6];
  const float* Wm = (const float*)d_in[7];
  const float* bm = (const float*)d_in[8];

  char* ws = (char*)d_ws;
  const size_t SZ = 16777216;
  short*  OA  = (short*)(ws + 0 * SZ);
  short*  h   = (short*)(ws + 1 * SZ);
  short*  l   = (short*)(ws + 2 * SZ);
  short*  gT  = (short*)(ws + 3 * SZ);
  short*  OB  = (short*)(ws + 4 * SZ);
  short*  Wt  = (short*)(ws + 5 * SZ);   // 2 MB
  float2* mlA = (float2*)(ws + 5 * SZ + 2097152);            // 128 KB
  float2* mlB = (float2*)(ws + 5 * SZ + 2097152 + 131072);   // 128 KB

  conv_w_kernel<<<4096, 256, 0, stream>>>(Wh, Wl, Wg, Wm, Wt);
  mlp3_kernel<<<dim3(128, 4, 3), 256, 0, stream>>>(x, Wt, bh, bl, bg, h, l, gT);
  attn_split_kernel<<<256, 512, 0, stream>>>(l, h, gT, OA, OB, mlA, mlB);
  final_gemm_kernel<<<dim3(128, 4), 256, 0, stream>>>(OA, OB, mlA, mlB, x,
                                                      Wt + 3 * 262144, bm,
                                                      (float*)d_out);
}

// Round 16
// 230.302 us; speedup vs baseline: 5.1598x; 1.0081x over previous
//
#include <hip/hip_runtime.h>

// B=8, N=2048, C=512. Flash attention + fp16 MFMA pipeline.
// r16: r15 base (232 µs) with conv_w rewritten as a coalesced LDS-transpose
// (64x64 f32 tiles, [64][65] pad; float4 reads, fp16x8 writes; 256 blocks vs
// 4096 strided-read blocks). attn/mlp3/final_gemm byte-frozen from r15.
// ws: [0]=OA [1]=h [2]=l [3]=gT [4]=OB [5]=Wt(2MB)+ml(256KB)

typedef __attribute__((ext_vector_type(4))) float f32x4;
typedef __attribute__((ext_vector_type(8))) short s16x8;      // fp16 bit-patterns
typedef __attribute__((ext_vector_type(4))) short s16x4;
typedef __attribute__((ext_vector_type(8))) _Float16 f16x8;   // MFMA operands
typedef __attribute__((ext_vector_type(4))) _Float16 f16x4;
typedef __attribute__((ext_vector_type(2))) unsigned u32x2;

typedef unsigned int u32;
typedef __attribute__((address_space(1))) const u32 gu32;
typedef __attribute__((address_space(3))) u32 lu32;

__device__ __forceinline__ void gload16(const short* g, short* l) {
  __builtin_amdgcn_global_load_lds((gu32*)g, (lu32*)l, 16, 0, 0);
}

__device__ __forceinline__ short f2h(float f) {
  _Float16 h = (_Float16)f;
  return __builtin_bit_cast(short, h);
}

__device__ __forceinline__ unsigned pk2h(float a, float b) {
  return __builtin_bit_cast(unsigned, __builtin_amdgcn_cvt_pkrtz(a, b));
}

#define MFMA(a, b, c) __builtin_amdgcn_mfma_f32_16x16x32_f16(a, b, c, 0, 0, 0)
#define MFMA16(a, b, c) __builtin_amdgcn_mfma_f32_16x16x16f16(a, b, c, 0, 0, 0)

#define BAR_KEEP2()                                          \
  do {                                                       \
    asm volatile("s_waitcnt vmcnt(2)" ::: "memory");         \
    __builtin_amdgcn_s_barrier();                            \
    __builtin_amdgcn_sched_barrier(0);                       \
  } while (0)
#define BAR_KEEP2_L()                                        \
  do {                                                       \
    asm volatile("s_waitcnt vmcnt(2) lgkmcnt(0)" ::: "memory"); \
    __builtin_amdgcn_s_barrier();                            \
    __builtin_amdgcn_sched_barrier(0);                       \
  } while (0)
#define BAR_KEEP4_L()                                        \
  do {                                                       \
    asm volatile("s_waitcnt vmcnt(4) lgkmcnt(0)" ::: "memory"); \
    __builtin_amdgcn_s_barrier();                            \
    __builtin_amdgcn_sched_barrier(0);                       \
  } while (0)
#define BAR_VM0()                                            \
  do {                                                       \
    asm volatile("s_waitcnt vmcnt(0)" ::: "memory");         \
    __builtin_amdgcn_s_barrier();                            \
    __builtin_amdgcn_sched_barrier(0);                       \
  } while (0)
#define BAR_ALL()                                            \
  do {                                                       \
    asm volatile("s_waitcnt vmcnt(0) lgkmcnt(0)" ::: "memory"); \
    __builtin_amdgcn_s_barrier();                            \
    __builtin_amdgcn_sched_barrier(0);                       \
  } while (0)

// ---------------- weight conversion: coalesced LDS transpose ----------------
// 256 blocks: (weight w, 8x8 grid of 64x64 tiles). Read float4 coalesced,
// transpose through [64][65] f32 LDS, write fp16x8 coalesced in k.

__global__ __launch_bounds__(256) void conv_w_kernel(const float* __restrict__ Wh,
                                                     const float* __restrict__ Wl,
                                                     const float* __restrict__ Wg,
                                                     const float* __restrict__ Wm,
                                                     short* __restrict__ Wt) {
  __shared__ float lds[64][65];
  int w = blockIdx.x >> 6, tile = blockIdx.x & 63;
  int tk = (tile >> 3) * 64, tn = (tile & 7) * 64;
  const float* W = (w == 0) ? Wh : (w == 1) ? Wl : (w == 2) ? Wg : Wm;
  int tid = threadIdx.x;

  int rr = tid >> 4, cc4 = (tid & 15) * 4;
#pragma unroll
  for (int p = 0; p < 4; ++p) {
    int row = rr + p * 16;  // k within tile
    float4 v = *(const float4*)&W[(size_t)(tk + row) * 512 + tn + cc4];
    lds[row][cc4] = v.x; lds[row][cc4 + 1] = v.y;
    lds[row][cc4 + 2] = v.z; lds[row][cc4 + 3] = v.w;
  }
  __syncthreads();

  int k8 = (tid & 7) * 8;
#pragma unroll
  for (int p = 0; p < 2; ++p) {
    int n = (tid >> 3) + p * 32;
    s16x8 o;
#pragma unroll
    for (int j = 0; j < 8; ++j) o[j] = f2h(lds[k8 + j][n]);
    *(s16x8*)&Wt[(size_t)w * 262144 + (size_t)(tn + n) * 512 + tk + k8] = o;
  }
}

// ---------------- fused cvt + 3-way MLP GEMM (pipelined, r15) ----------------

__global__ __launch_bounds__(256) void mlp3_kernel(const float* __restrict__ x,
                                                   const short* __restrict__ Wt_all,
                                                   const float* __restrict__ bh,
                                                   const float* __restrict__ bl,
                                                   const float* __restrict__ bg,
                                                   short* __restrict__ h,
                                                   short* __restrict__ l,
                                                   short* __restrict__ gT) {
  int z = blockIdx.z;
  const short* Wt = Wt_all + z * 262144;
  const float* bias = (z == 0) ? bh : (z == 1) ? bl : bg;

  __shared__ __align__(16) short abuf[2][4096];
  __shared__ __align__(16) short bbuf[3][4096];
  int tid = threadIdx.x, lane = tid & 63, w = tid >> 6;
  int wm = w >> 1, wn = w & 1;
  int bm = blockIdx.x * 128, bn = blockIdx.y * 128;
  int rx = lane & 15, g = lane >> 4;

  auto stageB = [&](int t) {
    int k0 = t * 32;
    short* bd = &bbuf[t % 3][0];
    int srow = lane >> 2;
    int scol = ((lane & 3) ^ ((lane >> 3) & 3)) * 8;
#pragma unroll
    for (int j = 0; j < 2; ++j) {
      int wl = w * 2 + j;
      int row = wl * 16 + srow;
      gload16(Wt + (size_t)(bn + row) * 512 + k0 + scol, bd + wl * 512 + lane * 8);
    }
  };
  auto loadA = [&](int t, s16x8 av[2]) {
#pragma unroll
    for (int it = 0; it < 2; ++it) {
      int c = tid + it * 256;
      int row = c >> 2, col8 = (c & 3) * 8;
      size_t base = (size_t)(bm + row) * 512 + t * 32 + col8;
      float4 x0 = *(const float4*)&x[base];
      float4 x1 = *(const float4*)&x[base + 4];
      s16x8 v;
      v[0] = f2h(x0.x); v[1] = f2h(x0.y); v[2] = f2h(x0.z); v[3] = f2h(x0.w);
      v[4] = f2h(x1.x); v[5] = f2h(x1.y); v[6] = f2h(x1.z); v[7] = f2h(x1.w);
      av[it] = v;
    }
  };
  auto writeA = [&](int t, s16x8 av[2]) {
    short* ad = &abuf[t & 1][0];
#pragma unroll
    for (int it = 0; it < 2; ++it) {
      int c = tid + it * 256;
      int row = c >> 2;
      int chunk_p = (c & 3) ^ ((row >> 1) & 3);
      *(s16x8*)&ad[row * 32 + chunk_p * 8] = av[it];
    }
  };

  f32x4 acc[4][4];
#pragma unroll
  for (int mi = 0; mi < 4; ++mi)
#pragma unroll
    for (int ni = 0; ni < 4; ++ni) acc[mi][ni] = (f32x4){0.f, 0.f, 0.f, 0.f};

  s16x8 av[2];
  loadA(0, av);
  stageB(0); stageB(1);
  writeA(0, av);
  BAR_KEEP2_L();

  int foff = rx * 32 + ((g ^ ((rx >> 1) & 3)) << 3);

  for (int t = 0; t < 16; ++t) {
    if (t < 15) loadA(t + 1, av);
    if (t < 14) stageB(t + 2);
    const short* ab = &abuf[t & 1][0];
    const short* bb = &bbuf[t % 3][0];
    f16x8 af[4], bfr[4];
#pragma unroll
    for (int mi = 0; mi < 4; ++mi)
      af[mi] = *(const f16x8*)&ab[(wm * 64 + mi * 16) * 32 + foff];
#pragma unroll
    for (int ni = 0; ni < 4; ++ni)
      bfr[ni] = *(const f16x8*)&bb[(wn * 64 + ni * 16) * 32 + foff];
#pragma unroll
    for (int mi = 0; mi < 4; ++mi)
#pragma unroll
      for (int ni = 0; ni < 4; ++ni) acc[mi][ni] = MFMA(af[mi], bfr[ni], acc[mi][ni]);
    if (t < 15) writeA(t + 1, av);
    if (t < 14) BAR_KEEP2_L();
    else if (t == 14) BAR_ALL();
  }

#pragma unroll
  for (int mi = 0; mi < 4; ++mi)
#pragma unroll
    for (int ni = 0; ni < 4; ++ni) {
      int col = bn + wn * 64 + ni * 16 + rx;
      float bv = bias[col];
#pragma unroll
      for (int r = 0; r < 4; ++r) {
        int row = bm + wm * 64 + mi * 16 + g * 4 + r;
        float v = fmaxf(acc[mi][ni][r] + bv, 0.0f);
        short o = f2h(v);
        if (z == 0) h[(size_t)row * 512 + col] = o;
        else if (z == 1) l[(size_t)row * 512 + col] = o;
        else {
          int bb2 = row >> 11, mm = row & 2047;
          gT[((size_t)bb2 * 512 + col) * 2048 + mm] = o;
        }
      }
    }
}

// ---------------- flash attention, split-K (r12 winner, frozen) ----------------

__global__ __launch_bounds__(512, 1) void attn_split_kernel(
    const short* __restrict__ lmat, const short* __restrict__ hmat,
    const short* __restrict__ gT,
    short* __restrict__ OA, short* __restrict__ OB,
    float2* __restrict__ mlA, float2* __restrict__ mlB) {
  __shared__ __align__(16) short kbuf[3][8192];  // 48KB
  __shared__ __align__(16) short gbuf[2][8192];  // 32KB
  int tid = threadIdx.x, lane = tid & 63, w = tid >> 6;  // w in 0..7
  int b = blockIdx.x & 7;
  int idx = blockIdx.x >> 3;
  int qt = idx >> 1, sp = idx & 1;
  int q0 = qt * 128 + w * 16;
  int keybase = sp * 1024;
  const short* lb = lmat + (size_t)b * 2048 * 512;
  const short* hb = hmat + (size_t)b * 2048 * 512;
  const short* gb = gT + (size_t)b * 512 * 2048;
  short* Op = sp ? OB : OA;
  float2* ml = sp ? mlB : mlA;

  int r0 = lane & 15, g = lane >> 4;

  f16x8 qf[16];
  {
    int q = q0 + r0;
#pragma unroll
    for (int ks = 0; ks < 16; ++ks)
      qf[ks] = *(const f16x8*)&lb[(size_t)q * 512 + ks * 32 + g * 8];
  }
  f32x4 accO[32];
#pragma unroll
  for (int i = 0; i < 32; ++i) accO[i] = (f32x4){0.f, 0.f, 0.f, 0.f};
  float mrun = -3e38f, lsumL = 0.f;

  auto stageK = [&](int t) {
    int key0 = keybase + t * 16;
    short* kd = &kbuf[t % 3][0];
#pragma unroll
    for (int j = 0; j < 2; ++j) {
      int wl = w * 2 + j;
      gload16(hb + (size_t)(key0 + wl) * 512 + (((lane * 16) ^ ((wl & 7) << 4)) >> 1),
              kd + wl * 512);
    }
  };
  auto stageG = [&](int t) {
    int key0 = keybase + t * 16;
    short* gd = &gbuf[t & 1][0];
#pragma unroll
    for (int j = 0; j < 2; ++j) {
      int wl = w * 2 + j;
      int c = wl * 32 + (lane >> 1);
      int half = (lane & 1) ^ ((lane >> 3) & 1);
      gload16(gb + (size_t)c * 2048 + key0 + half * 8, gd + wl * 512);
    }
  };
  auto QK = [&](int t, f32x4& o) {
    const short* kb = &kbuf[t % 3][0];
#pragma unroll
    for (int ks = 0; ks < 16; ++ks) {
      f16x8 kf = *(const f16x8*)&kb[(r0 * 512 + ks * 32 + g * 8) ^ ((r0 & 7) << 3)];
      o = MFMA(kf, qf[ks], o);
    }
  };

  stageK(0); stageK(1); stageG(0); stageK(2);
  BAR_KEEP2();
  f32x4 sc = {0.f, 0.f, 0.f, 0.f};
  QK(0, sc);
  BAR_KEEP2();

  int goff = r0 * 16 + (((g >> 1) ^ ((r0 >> 2) & 1)) << 3) + ((g & 1) << 2);

  for (int t = 0; t < 64; ++t) {
    if (t < 63) stageG(t + 1);
    if (t < 61) stageK(t + 3);

    f32x4 sn = {0.f, 0.f, 0.f, 0.f};
    if (t < 63) {
      __builtin_amdgcn_s_setprio(1);
      QK(t + 1, sn);
      __builtin_amdgcn_s_setprio(0);
    }

    float m2 = fmaxf(fmaxf(sc[0], sc[1]), fmaxf(sc[2], sc[3]));
    m2 = fmaxf(m2, __shfl_xor(m2, 16));
    m2 = fmaxf(m2, __shfl_xor(m2, 32));
    bool ok = (m2 <= mrun + 8.0f);
    if (!__all((int)ok)) {
      float mnew = fmaxf(mrun, m2);
      float s = __expf(mrun - mnew);
      mrun = mnew;
      lsumL *= s;
#pragma unroll
      for (int nf = 0; nf < 32; ++nf) accO[nf] *= s;
    }
    float p0 = __expf(sc[0] - mrun), p1 = __expf(sc[1] - mrun);
    float p2 = __expf(sc[2] - mrun), p3 = __expf(sc[3] - mrun);
    lsumL += (p0 + p1) + (p2 + p3);

    u32x2 pw = {pk2h(p0, p1), pk2h(p2, p3)};
    f16x4 pfrag = __builtin_bit_cast(f16x4, pw);

    const short* gp = &gbuf[t & 1][goff];
    __builtin_amdgcn_s_setprio(1);
#pragma unroll
    for (int nf = 0; nf < 32; ++nf) {
      f16x4 gf = *(const f16x4*)&gp[nf * 256];
      accO[nf] = MFMA16(gf, pfrag, accO[nf]);
    }
    __builtin_amdgcn_s_setprio(0);

    if (t < 61) BAR_KEEP2(); else BAR_VM0();
    sc = sn;
  }

  float ls = lsumL;
  ls += __shfl_xor(ls, 16);
  ls += __shfl_xor(ls, 32);
  float inv = 1.0f / ls;
  int q = q0 + r0;
#pragma unroll
  for (int nf = 0; nf < 32; ++nf) {
    s16x4 o;
    o[0] = f2h(accO[nf][0] * inv);
    o[1] = f2h(accO[nf][1] * inv);
    o[2] = f2h(accO[nf][2] * inv);
    o[3] = f2h(accO[nf][3] * inv);
    *(s16x4*)&Op[((size_t)b * 2048 + q) * 512 + nf * 16 + g * 4] = o;
  }
  if (g == 0) ml[(size_t)b * 2048 + q] = make_float2(mrun, ls);
}

// ---------------- fused combine + final GEMM (pipelined, r13, frozen) ----------------

__global__ __launch_bounds__(256) void final_gemm_kernel(
    const short* __restrict__ OA, const short* __restrict__ OB,
    const float2* __restrict__ mlA, const float2* __restrict__ mlB,
    const float* __restrict__ x, const short* __restrict__ Wt,
    const float* __restrict__ bias, float* __restrict__ out) {
  __shared__ __align__(16) short abuf[2][4096];
  __shared__ __align__(16) short bbuf[3][4096];
  int tid = threadIdx.x, lane = tid & 63, w = tid >> 6;
  int wm = w >> 1, wn = w & 1;
  int bm = blockIdx.x * 128, bn = blockIdx.y * 128;
  int rx = lane & 15, g = lane >> 4;

  float wgt[2][2];
#pragma unroll
  for (int it = 0; it < 2; ++it) {
    int row = (tid >> 2) + it * 64;
    float2 a2 = mlA[bm + row], b2 = mlB[bm + row];
    float ms = fmaxf(a2.x, b2.x);
    float wA = __expf(a2.x - ms) * a2.y;
    float wB = __expf(b2.x - ms) * b2.y;
    float winv = 1.0f / (wA + wB);
    wgt[it][0] = wA * winv;
    wgt[it][1] = wB * winv;
  }

  auto stageB = [&](int t) {
    int k0 = t * 32;
    short* bd = &bbuf[t % 3][0];
    int srow = lane >> 2;
    int scol = ((lane & 3) ^ ((lane >> 3) & 3)) * 8;
#pragma unroll
    for (int j = 0; j < 2; ++j) {
      int wl = w * 2 + j;
      int row = wl * 16 + srow;
      gload16(Wt + (size_t)(bn + row) * 512 + k0 + scol, bd + wl * 512 + lane * 8);
    }
  };
  auto loadA = [&](int t, s16x8 av[2]) {
#pragma unroll
    for (int it = 0; it < 2; ++it) {
      int c = tid + it * 256;
      int row = c >> 2, col8 = (c & 3) * 8;
      size_t base = (size_t)(bm + row) * 512 + t * 32 + col8;
      f16x8 oa = *(const f16x8*)&OA[base];
      f16x8 ob = *(const f16x8*)&OB[base];
      float4 x0 = *(const float4*)&x[base];
      float4 x1 = *(const float4*)&x[base + 4];
      float wA = wgt[it][0], wB = wgt[it][1];
      s16x8 v;
      v[0] = f2h((float)oa[0] * wA + (float)ob[0] * wB + x0.x);
      v[1] = f2h((float)oa[1] * wA + (float)ob[1] * wB + x0.y);
      v[2] = f2h((float)oa[2] * wA + (float)ob[2] * wB + x0.z);
      v[3] = f2h((float)oa[3] * wA + (float)ob[3] * wB + x0.w);
      v[4] = f2h((float)oa[4] * wA + (float)ob[4] * wB + x1.x);
      v[5] = f2h((float)oa[5] * wA + (float)ob[5] * wB + x1.y);
      v[6] = f2h((float)oa[6] * wA + (float)ob[6] * wB + x1.z);
      v[7] = f2h((float)oa[7] * wA + (float)ob[7] * wB + x1.w);
      av[it] = v;
    }
  };
  auto writeA = [&](int t, s16x8 av[2]) {
    short* ad = &abuf[t & 1][0];
#pragma unroll
    for (int it = 0; it < 2; ++it) {
      int c = tid + it * 256;
      int row = c >> 2;
      int chunk_p = (c & 3) ^ ((row >> 1) & 3);
      *(s16x8*)&ad[row * 32 + chunk_p * 8] = av[it];
    }
  };

  f32x4 acc[4][4];
#pragma unroll
  for (int mi = 0; mi < 4; ++mi)
#pragma unroll
    for (int ni = 0; ni < 4; ++ni) acc[mi][ni] = (f32x4){0.f, 0.f, 0.f, 0.f};

  s16x8 av[2];
  loadA(0, av);
  stageB(0); stageB(1);
  writeA(0, av);
  BAR_KEEP4_L();

  int foff = rx * 32 + ((g ^ ((rx >> 1) & 3)) << 3);

  for (int t = 0; t < 16; ++t) {
    if (t < 15) loadA(t + 1, av);
    if (t < 14) stageB(t + 2);
    const short* ab = &abuf[t & 1][0];
    const short* bb = &bbuf[t % 3][0];
    f16x8 af[4], bfr[4];
#pragma unroll
    for (int mi = 0; mi < 4; ++mi)
      af[mi] = *(const f16x8*)&ab[(wm * 64 + mi * 16) * 32 + foff];
#pragma unroll
    for (int ni = 0; ni < 4; ++ni)
      bfr[ni] = *(const f16x8*)&bb[(wn * 64 + ni * 16) * 32 + foff];
#pragma unroll
    for (int mi = 0; mi < 4; ++mi)
#pragma unroll
      for (int ni = 0; ni < 4; ++ni) acc[mi][ni] = MFMA(af[mi], bfr[ni], acc[mi][ni]);
    if (t < 15) writeA(t + 1, av);
    if (t < 14) BAR_KEEP4_L();
    else if (t == 14) BAR_ALL();
  }

#pragma unroll
  for (int mi = 0; mi < 4; ++mi)
#pragma unroll
    for (int ni = 0; ni < 4; ++ni) {
      int col = bn + wn * 64 + ni * 16 + rx;
      float bv = bias[col];
#pragma unroll
      for (int r = 0; r < 4; ++r) {
        int row = bm + wm * 64 + mi * 16 + g * 4 + r;
        out[(size_t)row * 512 + col] = fmaxf(acc[mi][ni][r] + bv, 0.0f);
      }
    }
}

// ---------------- host launch ----------------

extern "C" void kernel_launch(void* const* d_in, const int* in_sizes, int n_in,
                              void* d_out, int out_size, void* d_ws, size_t ws_size,
                              hipStream_t stream) {
  const float* x  = (const float*)d_in[0];
  const float* Wh = (const float*)d_in[1];
  const float* bh = (const float*)d_in[2];
  const float* Wl = (const float*)d_in[3];
  const float* bl = (const float*)d_in[4];
  const float* Wg = (const float*)d_in[5];
  const float* bg = (const float*)d_in[6];
  const float* Wm = (const float*)d_in[7];
  const float* bm = (const float*)d_in[8];

  char* ws = (char*)d_ws;
  const size_t SZ = 16777216;
  short*  OA  = (short*)(ws + 0 * SZ);
  short*  h   = (short*)(ws + 1 * SZ);
  short*  l   = (short*)(ws + 2 * SZ);
  short*  gT  = (short*)(ws + 3 * SZ);
  short*  OB  = (short*)(ws + 4 * SZ);
  short*  Wt  = (short*)(ws + 5 * SZ);   // 2 MB
  float2* mlA = (float2*)(ws + 5 * SZ + 2097152);            // 128 KB
  float2* mlB = (float2*)(ws + 5 * SZ + 2097152 + 131072);   // 128 KB

  conv_w_kernel<<<256, 256, 0, stream>>>(Wh, Wl, Wg, Wm, Wt);
  mlp3_kernel<<<dim3(128, 4, 3), 256, 0, stream>>>(x, Wt, bh, bl, bg, h, l, gT);
  attn_split_kernel<<<256, 512, 0, stream>>>(l, h, gT, OA, OB, mlA, mlB);
  final_gemm_kernel<<<dim3(128, 4), 256, 0, stream>>>(OA, OB, mlA, mlB, x,
                                                      Wt + 3 * 262144, bm,
                                                      (float*)d_out);
}